// Round 8
// baseline (65.937 us; speedup 1.0000x reference)
//
#include <hip/hip_runtime.h>
#include <math.h>

// out[n,s,d] = (x[n,s,d] + pe(s,d)) * mask[n,s,d]
//   pe(s,d) = sin(s*f(d)) if d even else cos(s*f(d)),  f(d)=10000^(-(d - d%2)/D)
// N=8, S=4096, D=1024 fp32.
//
// R7: hw transcendentals (v_sin/v_cos in revolutions) -> 59.8 us,
// VALUBusy 8.8%, aggregate vmem 6.73 TB/s (>= copy ceiling), but HBM-side
// only 4.5 TB/s: 50% read-hit in L3 (working set == 256 MiB L3, LRU thrash)
// + 128 MiB nt-store writes.
// R8 theory: invert the nt policy. Infinity Cache is MEMORY-SIDE (coherent
// for any reader), so normal stores let the 128 MiB output live in L3 and
// each graph replay overwrites the dirty lines IN-CACHE -> steady-state HBM
// writes ~0. nt-LOADS stream x+mask past L3 (no allocation) so they can't
// evict the output. HBM then carries only the 256 MiB mandatory read:
// ~43 us bound. Predict FETCH ~256 MiB, WRITE < 20 MiB, dur 43-53 us.

typedef float floatx4 __attribute__((ext_vector_type(4)));

constexpr int N = 8;
constexpr int S = 4096;
constexpr int D = 1024;
constexpr int DV = D / 4;                 // float4 per row (=256)
constexpr int SD4 = S * DV;               // float4 per batch slice (=2^20)
constexpr int TOTAL = N * SD4;            // 8M float4

__device__ __forceinline__ float hw_sin_rev(float rev) {
    float fr = rev - floorf(rev);         // v_fract
    float r;
    asm("v_sin_f32 %0, %1" : "=v"(r) : "v"(fr));
    return r;                             // sin(2*pi*fr)
}
__device__ __forceinline__ float hw_cos_rev(float rev) {
    float fr = rev - floorf(rev);
    float r;
    asm("v_cos_f32 %0, %1" : "=v"(r) : "v"(fr));
    return r;                             // cos(2*pi*fr)
}

__global__ __launch_bounds__(256)
void PositionalEncoding_78855599554887_kernel(const floatx4* __restrict__ x,
                                              const floatx4* __restrict__ mask,
                                              floatx4* __restrict__ out) {
    const int t = blockIdx.x * blockDim.x + threadIdx.x;   // [0, TOTAL)

    // decode (s, d4) — n is irrelevant to PE
    const int d4 = t & (DV - 1);              // float4 index along D
    const int s  = (t >> 8) & (S - 1);        // row index within slice

    // rev(d) = s * 10000^(-d/D) / (2*pi) = s * exp2(d*c2 + k)
    const float c2 = -0.012976282f;           // -log2(10000)/1024
    const float k  = -2.6514961f;             // -log2(2*pi)
    const float db = (float)(d4 * 4);         // even base d
    const float fs = (float)s;
    const float rev0 = fs * exp2f(db * c2 + k);            // d = 4k, 4k+1
    const float rev1 = fs * exp2f((db + 2.0f) * c2 + k);   // d = 4k+2, 4k+3

    floatx4 pe;
    pe.x = hw_sin_rev(rev0);
    pe.y = hw_cos_rev(rev0);
    pe.z = hw_sin_rev(rev1);
    pe.w = hw_cos_rev(rev1);

    // nt-loads: stream past L3, don't evict the L3-resident output lines
    const floatx4 xv = __builtin_nontemporal_load(&x[t]);
    const floatx4 mv = __builtin_nontemporal_load(&mask[t]);
    floatx4 o = (xv + pe) * mv;
    out[t] = o;                               // normal store: write-allocate in L3
}

extern "C" void kernel_launch(void* const* d_in, const int* in_sizes, int n_in,
                              void* d_out, int out_size, void* d_ws, size_t ws_size,
                              hipStream_t stream) {
    const floatx4* x    = (const floatx4*)d_in[0];
    const floatx4* mask = (const floatx4*)d_in[1];
    floatx4* out        = (floatx4*)d_out;

    const int threads = 256;
    const int blocks  = TOTAL / threads;      // 32768 blocks, exact cover
    PositionalEncoding_78855599554887_kernel<<<blocks, threads, 0, stream>>>(x, mask, out);
}

// Round 9
// 59.710 us; speedup vs baseline: 1.1043x; 1.1043x over previous
//
#include <hip/hip_runtime.h>
#include <math.h>

// out[n,s,d] = (x[n,s,d] + pe(s,d)) * mask[n,s,d]
//   pe(s,d) = sin(s*f(d)) if d even else cos(s*f(d)),  f(d)=10000^(-(d - d%2)/D)
// N=8, S=4096, D=1024 fp32.
//
// FINAL (= R7 config, reverting R8):
//   - copy-kernel shape: 1 float4/thread, 32768 x 256, pure TLP (R5: 24
//     streams/wave with batch-of-8 was 3.4 TB/s; this shape 6.5+ TB/s)
//   - hw transcendentals: rev = s*exp2(d*c2 + k) (revolutions), fract,
//     v_sin_f32/v_cos_f32 (R7: VALUBusy 19.5% -> 8.8%)
//   - normal loads (L3 serves ~50% of the 256 MiB read stream)
//   - nontemporal stores (write-once output, don't evict input lines)
// R8 tested the inverted nt policy (nt-loads + normal stores): 65.9 us,
// refuted. R7 = 59.8 us = 6.73 TB/s aggregate vmem, above the 6.29 TB/s
// copy ceiling -> mixed-stream fabric roofline.

typedef float floatx4 __attribute__((ext_vector_type(4)));

constexpr int N = 8;
constexpr int S = 4096;
constexpr int D = 1024;
constexpr int DV = D / 4;                 // float4 per row (=256)
constexpr int SD4 = S * DV;               // float4 per batch slice (=2^20)
constexpr int TOTAL = N * SD4;            // 8M float4

__device__ __forceinline__ float hw_sin_rev(float rev) {
    float fr = rev - floorf(rev);         // v_fract
    float r;
    asm("v_sin_f32 %0, %1" : "=v"(r) : "v"(fr));
    return r;                             // sin(2*pi*fr)
}
__device__ __forceinline__ float hw_cos_rev(float rev) {
    float fr = rev - floorf(rev);
    float r;
    asm("v_cos_f32 %0, %1" : "=v"(r) : "v"(fr));
    return r;                             // cos(2*pi*fr)
}

__global__ __launch_bounds__(256)
void PositionalEncoding_78855599554887_kernel(const floatx4* __restrict__ x,
                                              const floatx4* __restrict__ mask,
                                              floatx4* __restrict__ out) {
    const int t = blockIdx.x * blockDim.x + threadIdx.x;   // [0, TOTAL)

    // decode (s, d4) — n is irrelevant to PE
    const int d4 = t & (DV - 1);              // float4 index along D
    const int s  = (t >> 8) & (S - 1);        // row index within slice

    // rev(d) = s * 10000^(-d/D) / (2*pi) = s * exp2(d*c2 + k)
    const float c2 = -0.012976282f;           // -log2(10000)/1024
    const float k  = -2.6514961f;             // -log2(2*pi)
    const float db = (float)(d4 * 4);         // even base d
    const float fs = (float)s;
    const float rev0 = fs * exp2f(db * c2 + k);            // d = 4k, 4k+1
    const float rev1 = fs * exp2f((db + 2.0f) * c2 + k);   // d = 4k+2, 4k+3

    floatx4 pe;
    pe.x = hw_sin_rev(rev0);
    pe.y = hw_cos_rev(rev0);
    pe.z = hw_sin_rev(rev1);
    pe.w = hw_cos_rev(rev1);

    const floatx4 xv = x[t];
    const floatx4 mv = mask[t];
    floatx4 o = (xv + pe) * mv;
    __builtin_nontemporal_store(o, &out[t]);
}

extern "C" void kernel_launch(void* const* d_in, const int* in_sizes, int n_in,
                              void* d_out, int out_size, void* d_ws, size_t ws_size,
                              hipStream_t stream) {
    const floatx4* x    = (const floatx4*)d_in[0];
    const floatx4* mask = (const floatx4*)d_in[1];
    floatx4* out        = (floatx4*)d_out;

    const int threads = 256;
    const int blocks  = TOTAL / threads;      // 32768 blocks, exact cover
    PositionalEncoding_78855599554887_kernel<<<blocks, threads, 0, stream>>>(x, mask, out);
}